// Round 6
// baseline (189.087 us; speedup 1.0000x reference)
//
#include <hip/hip_runtime.h>
#include <hip/hip_bf16.h>

typedef __bf16 bf16_t;
typedef __bf16 bf16x8 __attribute__((ext_vector_type(8)));
typedef float  f32x4  __attribute__((ext_vector_type(4)));
typedef int    i32x8  __attribute__((ext_vector_type(8)));

__device__ __forceinline__ bf16x8 pack8(f32x4 a, f32x4 b) {
    bf16x8 h = { (bf16_t)a.x, (bf16_t)a.y, (bf16_t)a.z, (bf16_t)a.w,
                 (bf16_t)b.x, (bf16_t)b.y, (bf16_t)b.z, (bf16_t)b.w };
    return h;
}

// 16B async global->LDS DMA. LDS dest is wave-uniform base + lane*16.
__device__ __forceinline__ void gl_lds16(const void* g, void* l) {
    __builtin_amdgcn_global_load_lds(
        (const __attribute__((address_space(1))) unsigned int*)g,
        (__attribute__((address_space(3))) unsigned int*)l, 16, 0, 0);
}

// ---- fp8 e4m3 (OCP) conversion ----
#if __has_builtin(__builtin_amdgcn_cvt_pk_fp8_f32)
__device__ __forceinline__ unsigned char cvt1_e4m3(float x) {
    return (unsigned char)(__builtin_amdgcn_cvt_pk_fp8_f32(x, x, 0, false) & 0xff);
}
#else
__device__ __forceinline__ unsigned char cvt1_e4m3(float x) {
    unsigned u = __float_as_uint(x);
    unsigned sign = (u >> 24) & 0x80u;
    float a = fabsf(x);
    if (a < 7.8125e-3f) { int q = (int)(a * 512.0f + 0.5f); return (unsigned char)(sign | q); }
    if (a >= 448.0f) return (unsigned char)(sign | 0x7E);
    unsigned au = u & 0x7FFFFFFFu;
    unsigned lsb = (au >> 20) & 1u;
    au += 0x7FFFFu + lsb;
    int exp = (int)(au >> 23) - 127;
    unsigned man = (au >> 20) & 7u;
    return (unsigned char)(sign | ((unsigned)(exp + 7) << 3) | man);
}
#endif

// Fragment-major ELEMENT offset within a 16-row tile (any K) — bf16 16x16x32
// operand layout (used for W only).
__device__ __forceinline__ int frag_off_k(int row16, int k) {
    return ((k >> 6) << 10) + (((k >> 3) & 3) << 8) + (row16 << 4)
         + (((k >> 5) & 1) << 3) + (k & 7);
}

// ---------------------------------------------------------------------------
// wconv: W (fp32 [256,K]) -> fragment-major bf16.
// ---------------------------------------------------------------------------
__global__ __launch_bounds__(256) void wconv(
    const float* __restrict__ Wx, const float* __restrict__ Wy,
    bf16_t* __restrict__ Wxt, bf16_t* __restrict__ Wyt)
{
    int id = blockIdx.x * 256 + threadIdx.x;

    int row, k0, K;
    const float* W;
    bf16_t* Wt;
    if (id < 32768) { W = Wx; Wt = Wxt; K = 1024; row = id >> 7; k0 = (id & 127) << 3; }
    else { int c = id - 32768; W = Wy; Wt = Wyt; K = 768; row = c / 96; k0 = (c % 96) << 3; }

    f32x4 lo = *reinterpret_cast<const f32x4*>(&W[(size_t)row * K + k0]);
    f32x4 hi = *reinterpret_cast<const f32x4*>(&W[(size_t)row * K + k0 + 4]);
    size_t off = (size_t)(row >> 4) * 16 * K + frag_off_k(row & 15, k0);
    *reinterpret_cast<bf16x8*>(Wt + off) = pack8(lo, hi);
}

// ---------------------------------------------------------------------------
// proj_norm: P = A@W^T + bias -> L2 row-normalize -> fp8 stored in the
// MX-scaled K=128 fragment layout:
//   per 16-row tile (4096 B): off = (k>>5)*512 + row16*32 + (k&31)
// (UNCHANGED.)
// ---------------------------------------------------------------------------
__global__ __launch_bounds__(512, 2) void proj_norm(
    const float* __restrict__ X, const float* __restrict__ Y,
    const bf16_t* __restrict__ Wxt, const float* __restrict__ bxp,
    const bf16_t* __restrict__ Wyt, const float* __restrict__ byp,
    unsigned char* __restrict__ Xt, unsigned char* __restrict__ Yt)
{
    __shared__ float Abuf[2][64 * 64];       // 16 KB x2, chunk-XOR swizzled
    __shared__ unsigned char obuf[16384];    // 64x256 fp8 frag-major (MX layout)
    __shared__ float ssqL[4][64];            // [colGroup][row]

    const int tid  = threadIdx.x;
    const int lane = tid & 63;
    const int wave = tid >> 6;     // 0..7
    const int quad = lane >> 4;
    const int c16  = lane & 15;
    const int rg   = wave >> 2;    // 0..1: rows rg*32
    const int cg   = wave & 3;     // 0..3: cols cg*64

    const bool isY = blockIdx.x >= 128;
    const float*  A    = isY ? Y   : X;
    const bf16_t* Wt   = isY ? Wyt : Wxt;
    const float*  bias = isY ? byp : bxp;
    unsigned char* dst = isY ? Yt  : Xt;
    const int K = isY ? 768 : 1024;
    const int S = K >> 6;           // 64-K slabs
    const int rowBase = (blockIdx.x & 127) * 64;

    // DMA slab s into buffer b: 2 instrs/thread, wave moves 8 rows x 256B
    auto stage = [&](int s, int b) {
        #pragma unroll
        for (int t = 0; t < 2; ++t) {
            int r0  = (wave * 2 + t) * 4;            // wave-uniform base row
            int row = r0 + (lane >> 4);
            int gch = (lane & 15) ^ (row & 15);      // swizzled source chunk
            gl_lds16(&A[(size_t)(rowBase + row) * K + s * 64 + gch * 4],
                     &Abuf[b][r0 * 64]);
        }
    };

    // A fragment: row = rg*32 + mf*16 + c16 (row&15 == c16)
    auto aFrag = [&](int b, int mf, int s2) -> bf16x8 {
        int row = rg * 32 + mf * 16 + c16;
        int e   = s2 * 8 + quad * 2;                 // even 16B-chunk index
        const float* base = &Abuf[b][row * 64];
        f32x4 lo = *reinterpret_cast<const f32x4*>(base + ((e ^ c16) << 2));
        f32x4 hi = *reinterpret_cast<const f32x4*>(base + (((e + 1) ^ c16) << 2));
        return pack8(lo, hi);
    };

    const bf16_t* pB[4];
    #pragma unroll
    for (int nf = 0; nf < 4; ++nf)
        pB[nf] = Wt + (size_t)(cg * 4 + nf) * 16 * K + quad * 256 + c16 * 16;

    f32x4 acc[2][4] = {};
    stage(0, 0);

    for (int s = 0; s < S; ++s) {
        const int b = s & 1;
        __syncthreads();                   // drains buf b's DMA (issued 1 iter ago)
        if (s + 1 < S) stage(s + 1, b ^ 1);
        #pragma unroll
        for (int s2 = 0; s2 < 2; ++s2) {
            bf16x8 bF[4];
            #pragma unroll
            for (int nf = 0; nf < 4; ++nf)
                bF[nf] = *reinterpret_cast<const bf16x8*>(pB[nf] + s * 1024 + s2 * 8);
            #pragma unroll
            for (int mf = 0; mf < 2; ++mf) {
                bf16x8 aF = aFrag(b, mf, s2);
                #pragma unroll
                for (int nf = 0; nf < 4; ++nf)
                    acc[mf][nf] = __builtin_amdgcn_mfma_f32_16x16x32_bf16(
                        aF, bF[nf], acc[mf][nf], 0, 0, 0);
            }
        }
    }

    // ---- epilogue: +bias, ssq, normalize, fp8 MX-frag store ----
    #pragma unroll
    for (int nf = 0; nf < 4; ++nf) {
        float bb = bias[cg * 64 + nf * 16 + c16];
        #pragma unroll
        for (int mf = 0; mf < 2; ++mf)
            #pragma unroll
            for (int r = 0; r < 4; ++r) acc[mf][nf][r] += bb;
    }

    #pragma unroll
    for (int mf = 0; mf < 2; ++mf)
        #pragma unroll
        for (int r = 0; r < 4; ++r) {
            float v = 0.f;
            #pragma unroll
            for (int nf = 0; nf < 4; ++nf) v += acc[mf][nf][r] * acc[mf][nf][r];
            v += __shfl_xor(v, 1, 64);
            v += __shfl_xor(v, 2, 64);
            v += __shfl_xor(v, 4, 64);
            v += __shfl_xor(v, 8, 64);
            if (c16 == 0) ssqL[cg][rg * 32 + mf * 16 + quad * 4 + r] = v;
        }
    __syncthreads();

    #pragma unroll
    for (int mf = 0; mf < 2; ++mf)
        #pragma unroll
        for (int r = 0; r < 4; ++r) {
            int lr = rg * 32 + mf * 16 + quad * 4 + r;
            float t = ssqL[0][lr] + ssqL[1][lr] + ssqL[2][lr] + ssqL[3][lr];
            float inv = 1.0f / fmaxf(sqrtf(t), 1e-8f);
            #pragma unroll
            for (int nf = 0; nf < 4; ++nf) {
                int k = cg * 64 + nf * 16 + c16;
                // MX K=128 operand layout: (k>>5)*512 + row16*32 + (k&31)
                obuf[((lr >> 4) << 12) + ((k >> 5) << 9) + ((lr & 15) << 5) + (k & 31)] =
                    cvt1_e4m3(acc[mf][nf][r] * inv);
            }
        }
    __syncthreads();

    // coalesced copy-out: 16 KB, 32 B/thread (tiles contiguous in global)
    const f32x4* src = reinterpret_cast<const f32x4*>(&obuf[tid * 32]);
    f32x4* g = reinterpret_cast<f32x4*>(dst + (size_t)rowBase * 256 + tid * 32);
    g[0] = src[0];
    g[1] = src[1];
}

// ---------------------------------------------------------------------------
// sim_gemm: e = exp(Xn @ Yn^T); partial rowsum/colsum/diag.
// ROUND 6: intra-wave software pipeline at mf granularity, zero extra
// registers. Per tile, 4 phases: after phase mf's 8 MFMAs are ISSUED,
// run phase mf-1's epilogue (exp/reduce VALU) while they execute, and
// spread the next-tile A prefetch one mf per phase. sched_barrier(0)
// pins phase boundaries (register-only phases); setprio(1) on MFMA.
// Keeps R5's barrier-free/LDS-free/atomic-free structure.
// ---------------------------------------------------------------------------
__global__ __launch_bounds__(256, 2) void sim_gemm(
    const unsigned char* __restrict__ Xt, const unsigned char* __restrict__ Yt,
    float* __restrict__ rowsumP, float* __restrict__ colsumP,
    float* __restrict__ pos)
{
    const int tid  = threadIdx.x;
    const int lane = tid & 63;
    const int wave = tid >> 6;
    const int quad = lane >> 4;
    const int c16  = lane & 15;
    const int wy   = wave >> 1;
    const int wx   = wave & 1;

    // id&7 = XCD; each XCD: 8 colBlks x 16 row-groups (x4 tiles each).
    const int id = blockIdx.x;                     // 0..1023
    const int b2 = id >> 3;                        // 0..127
    const int colBlk = (id & 7) * 8 + (b2 >> 4);   // 0..63
    const int rowGrp = b2 & 15;                    // 0..15 -> rows rowGrp*512..
    const int colBase = colBlk * 128;

    // ---- B fragments: load once ----
    i32x8 B0[4], B1[4];
    #pragma unroll
    for (int nf = 0; nf < 4; ++nf) {
        const i32x8* p = reinterpret_cast<const i32x8*>(
            Yt + (size_t)(colBase + wx * 64 + nf * 16) * 256 + quad * 512 + c16 * 32);
        B0[nf] = p[0];
        B1[nf] = p[64];
    }

    auto aPtr = [&](int rowBase, int mf) {
        return reinterpret_cast<const i32x8*>(
            Xt + (size_t)(rowBase + wy * 64 + mf * 16) * 256 + quad * 512 + c16 * 32);
    };

    // ---- A fragments for tile 0 ----
    i32x8 A0[4], A1[4];
    #pragma unroll
    for (int mf = 0; mf < 4; ++mf) {
        const i32x8* p = aPtr(rowGrp * 512, mf);
        A0[mf] = p[0];
        A1[mf] = p[64];
    }

    float cs[4] = {0.f, 0.f, 0.f, 0.f};   // per-lane colsum partials across tiles

    #pragma unroll
    for (int t = 0; t < 4; ++t) {
        const int rowBase = rowGrp * 512 + t * 128;
        const bool diag = (rowBase == colBase);

        f32x4 acc[4][4] = {};
        float rs[4][4];

        // 8 MFMAs of one mf phase (A0 cluster then A1 cluster)
        auto MFMA8 = [&](int mf) {
            __builtin_amdgcn_s_setprio(1);
            #pragma unroll
            for (int nf = 0; nf < 4; ++nf)
                acc[mf][nf] = __builtin_amdgcn_mfma_scale_f32_16x16x128_f8f6f4(
                    A0[mf], B0[nf], acc[mf][nf], 0, 0, 0, 127, 0, 127);
            #pragma unroll
            for (int nf = 0; nf < 4; ++nf)
                acc[mf][nf] = __builtin_amdgcn_mfma_scale_f32_16x16x128_f8f6f4(
                    A1[mf], B1[nf], acc[mf][nf], 0, 0, 0, 127, 0, 127);
            __builtin_amdgcn_s_setprio(0);
        };
        // next-tile A prefetch for one mf (WAR on issued MFMAs is
        // scoreboard-handled; consumer is 3+ phases away)
        auto PF = [&](int mf) {
            if (t < 3) {
                const i32x8* p = aPtr(rowBase + 128, mf);
                A0[mf] = p[0];
                A1[mf] = p[64];
            }
        };
        // epilogue for one mf: exp, diag store, rowsum partial, colsum acc
        auto EPI = [&](int mf) {
            #pragma unroll
            for (int nf = 0; nf < 4; ++nf)
                #pragma unroll
                for (int r = 0; r < 4; ++r)
                    acc[mf][nf][r] = __expf(acc[mf][nf][r]);   // TAU = 1
            if (diag) {
                #pragma unroll
                for (int nf = 0; nf < 4; ++nf)
                    #pragma unroll
                    for (int r = 0; r < 4; ++r) {
                        int lrow = wy * 64 + mf * 16 + quad * 4 + r;
                        int lcol = wx * 64 + nf * 16 + c16;
                        if (lrow == lcol) pos[rowBase + lrow] = acc[mf][nf][r];
                    }
            }
            #pragma unroll
            for (int r = 0; r < 4; ++r) {
                float v = acc[mf][0][r] + acc[mf][1][r] + acc[mf][2][r] + acc[mf][3][r];
                v += __shfl_xor(v, 1, 64);
                v += __shfl_xor(v, 2, 64);
                v += __shfl_xor(v, 4, 64);
                v += __shfl_xor(v, 8, 64);
                rs[mf][r] = v;
            }
            #pragma unroll
            for (int nf = 0; nf < 4; ++nf)
                cs[nf] += (acc[mf][nf][0] + acc[mf][nf][1])
                        + (acc[mf][nf][2] + acc[mf][nf][3]);
        };

        // ---- 4-phase pipeline: MFMA(mf) executes under EPI(mf-1) ----
        MFMA8(0);
        __builtin_amdgcn_sched_barrier(0);
        PF(0);
        MFMA8(1);
        __builtin_amdgcn_sched_barrier(0);
        EPI(0);
        __builtin_amdgcn_sched_barrier(0);
        PF(1);
        MFMA8(2);
        __builtin_amdgcn_sched_barrier(0);
        EPI(1);
        __builtin_amdgcn_sched_barrier(0);
        PF(2);
        MFMA8(3);
        __builtin_amdgcn_sched_barrier(0);
        EPI(2);
        __builtin_amdgcn_sched_barrier(0);
        PF(3);
        EPI(3);

        // ---- tile tail: register lane-transpose + ONE coalesced store ----
        // lane L ends with the sum for row wy*64+L (harness-verified R4/R5).
        float vsel = rs[0][0];
        #pragma unroll
        for (int k = 1; k < 16; ++k)
            vsel = (c16 == k) ? rs[k >> 2][k & 3] : vsel;
        int srcLane = ((lane >> 2) & 3) * 16 + (lane >> 4) * 4 + (lane & 3);
        float rowv = __shfl(vsel, srcLane, 64);
        rowsumP[(size_t)(colBlk * 2 + wx) * 8192 + rowBase + wy * 64 + lane] = rowv;
    }

    // ---- colsum: xor-reduce over quad bits; lane L selects cs[L>>4]
    // (its col is wx*64 + L). One coalesced PLAIN store per wave. ----
    #pragma unroll
    for (int nf = 0; nf < 4; ++nf) {
        float v = cs[nf];
        v += __shfl_xor(v, 16, 64);
        v += __shfl_xor(v, 32, 64);
        cs[nf] = v;
    }
    float csel = cs[0];
    #pragma unroll
    for (int k = 1; k < 4; ++k)
        csel = (quad == k) ? cs[k] : csel;
    colsumP[(size_t)(rowGrp * 2 + wy) * 8192 + colBase + wx * 64 + lane] = csel;
}

// ---------------------------------------------------------------------------
// finalize: parallelized slab reduction. 256 blocks x 256 threads; each
// block owns 32 outputs, 8 threads per output (coalesced slab-major reads),
// LDS combine, then the log expression.
// ---------------------------------------------------------------------------
__global__ __launch_bounds__(256) void finalize(
    const float* __restrict__ rowsumP, const float* __restrict__ colsumP,
    const float* __restrict__ pos, float* __restrict__ out)
{
    __shared__ float redR[256], redC[256];

    const int oi   = threadIdx.x & 31;      // output within block
    const int part = threadIdx.x >> 5;      // 0..7
    const int i    = blockIdx.x * 32 + oi;

    float r = 0.f;
    #pragma unroll
    for (int c = part; c < 128; c += 8)
        r += rowsumP[(size_t)c * 8192 + i];

    float cv = 0.f;
    #pragma unroll
    for (int g = part; g < 32; g += 8)
        cv += colsumP[(size_t)g * 8192 + i];

    redR[threadIdx.x] = r;
    redC[threadIdx.x] = cv;
    __syncthreads();

    if (threadIdx.x < 32) {
        float rsum = 0.f, csum = 0.f;
        #pragma unroll
        for (int p = 0; p < 8; ++p) {
            rsum += redR[oi + 32 * p];
            csum += redC[oi + 32 * p];
        }
        float p = pos[i];
        out[i] = logf(csum - p) + logf(rsum - p) - 2.0f * logf(p);
    }
}

// ---------------------------------------------------------------------------
extern "C" void kernel_launch(void* const* d_in, const int* in_sizes, int n_in,
                              void* d_out, int out_size, void* d_ws, size_t ws_size,
                              hipStream_t stream) {
    const float* X  = (const float*)d_in[0];
    const float* Y  = (const float*)d_in[1];
    const float* Wx = (const float*)d_in[2];
    const float* bx = (const float*)d_in[3];
    const float* Wy = (const float*)d_in[4];
    const float* by = (const float*)d_in[5];
    float* out = (float*)d_out;

    char* ws = (char*)d_ws;
    unsigned char* Xt  = (unsigned char*)(ws);               // 2 MB fp8 MX frag-major
    unsigned char* Yt  = (unsigned char*)(ws + (2u << 20));  // 2 MB
    bf16_t*        Wxt = (bf16_t*)(ws + (4u << 20));         // 512 KB bf16 frag-major
    bf16_t*        Wyt = (bf16_t*)(ws + (4u << 20) + (512u << 10));  // 384 KB
    float* rowsumP = (float*)(ws + (5u << 20));              // 128 x 8192 f32 = 4 MB
    float* colsumP = (float*)(ws + (9u << 20));              //  32 x 8192 f32 = 1 MB
    float* pos     = (float*)(ws + (10u << 20));             // 32 KB

    wconv<<<224, 256, 0, stream>>>(Wx, Wy, Wxt, Wyt);
    proj_norm<<<256, 512, 0, stream>>>(X, Y, Wxt, bx, Wyt, by, Xt, Yt);
    sim_gemm<<<1024, 256, 0, stream>>>(Xt, Yt, rowsumP, colsumP, pos);
    finalize<<<256, 256, 0, stream>>>(rowsumP, colsumP, pos, out);
}

// Round 7
// 184.190 us; speedup vs baseline: 1.0266x; 1.0266x over previous
//
#include <hip/hip_runtime.h>
#include <hip/hip_bf16.h>

typedef __bf16 bf16_t;
typedef __bf16 bf16x8 __attribute__((ext_vector_type(8)));
typedef float  f32x4  __attribute__((ext_vector_type(4)));
typedef int    i32x8  __attribute__((ext_vector_type(8)));

__device__ __forceinline__ bf16x8 pack8(f32x4 a, f32x4 b) {
    bf16x8 h = { (bf16_t)a.x, (bf16_t)a.y, (bf16_t)a.z, (bf16_t)a.w,
                 (bf16_t)b.x, (bf16_t)b.y, (bf16_t)b.z, (bf16_t)b.w };
    return h;
}

// 16B async global->LDS DMA. LDS dest is wave-uniform base + lane*16.
__device__ __forceinline__ void gl_lds16(const void* g, void* l) {
    __builtin_amdgcn_global_load_lds(
        (const __attribute__((address_space(1))) unsigned int*)g,
        (__attribute__((address_space(3))) unsigned int*)l, 16, 0, 0);
}

// ---- fp8 e4m3 (OCP) conversion ----
#if __has_builtin(__builtin_amdgcn_cvt_pk_fp8_f32)
__device__ __forceinline__ unsigned char cvt1_e4m3(float x) {
    return (unsigned char)(__builtin_amdgcn_cvt_pk_fp8_f32(x, x, 0, false) & 0xff);
}
#else
__device__ __forceinline__ unsigned char cvt1_e4m3(float x) {
    unsigned u = __float_as_uint(x);
    unsigned sign = (u >> 24) & 0x80u;
    float a = fabsf(x);
    if (a < 7.8125e-3f) { int q = (int)(a * 512.0f + 0.5f); return (unsigned char)(sign | q); }
    if (a >= 448.0f) return (unsigned char)(sign | 0x7E);
    unsigned au = u & 0x7FFFFFFFu;
    unsigned lsb = (au >> 20) & 1u;
    au += 0x7FFFFu + lsb;
    int exp = (int)(au >> 23) - 127;
    unsigned man = (au >> 20) & 7u;
    return (unsigned char)(sign | ((unsigned)(exp + 7) << 3) | man);
}
#endif

// Fragment-major ELEMENT offset within a 16-row tile (any K) — bf16 16x16x32
// operand layout (used for W only).
__device__ __forceinline__ int frag_off_k(int row16, int k) {
    return ((k >> 6) << 10) + (((k >> 3) & 3) << 8) + (row16 << 4)
         + (((k >> 5) & 1) << 3) + (k & 7);
}

// ---------------------------------------------------------------------------
// wconv: W (fp32 [256,K]) -> fragment-major bf16.
// ---------------------------------------------------------------------------
__global__ __launch_bounds__(256) void wconv(
    const float* __restrict__ Wx, const float* __restrict__ Wy,
    bf16_t* __restrict__ Wxt, bf16_t* __restrict__ Wyt)
{
    int id = blockIdx.x * 256 + threadIdx.x;

    int row, k0, K;
    const float* W;
    bf16_t* Wt;
    if (id < 32768) { W = Wx; Wt = Wxt; K = 1024; row = id >> 7; k0 = (id & 127) << 3; }
    else { int c = id - 32768; W = Wy; Wt = Wyt; K = 768; row = c / 96; k0 = (c % 96) << 3; }

    f32x4 lo = *reinterpret_cast<const f32x4*>(&W[(size_t)row * K + k0]);
    f32x4 hi = *reinterpret_cast<const f32x4*>(&W[(size_t)row * K + k0 + 4]);
    size_t off = (size_t)(row >> 4) * 16 * K + frag_off_k(row & 15, k0);
    *reinterpret_cast<bf16x8*>(Wt + off) = pack8(lo, hi);
}

// ---------------------------------------------------------------------------
// proj_norm: P = A@W^T + bias -> L2 row-normalize -> fp8 stored in the
// MX-scaled K=128 fragment layout:
//   per 16-row tile (4096 B): off = (k>>5)*512 + row16*32 + (k&31)
// (UNCHANGED.)
// ---------------------------------------------------------------------------
__global__ __launch_bounds__(512, 2) void proj_norm(
    const float* __restrict__ X, const float* __restrict__ Y,
    const bf16_t* __restrict__ Wxt, const float* __restrict__ bxp,
    const bf16_t* __restrict__ Wyt, const float* __restrict__ byp,
    unsigned char* __restrict__ Xt, unsigned char* __restrict__ Yt)
{
    __shared__ float Abuf[2][64 * 64];       // 16 KB x2, chunk-XOR swizzled
    __shared__ unsigned char obuf[16384];    // 64x256 fp8 frag-major (MX layout)
    __shared__ float ssqL[4][64];            // [colGroup][row]

    const int tid  = threadIdx.x;
    const int lane = tid & 63;
    const int wave = tid >> 6;     // 0..7
    const int quad = lane >> 4;
    const int c16  = lane & 15;
    const int rg   = wave >> 2;    // 0..1: rows rg*32
    const int cg   = wave & 3;     // 0..3: cols cg*64

    const bool isY = blockIdx.x >= 128;
    const float*  A    = isY ? Y   : X;
    const bf16_t* Wt   = isY ? Wyt : Wxt;
    const float*  bias = isY ? byp : bxp;
    unsigned char* dst = isY ? Yt  : Xt;
    const int K = isY ? 768 : 1024;
    const int S = K >> 6;           // 64-K slabs
    const int rowBase = (blockIdx.x & 127) * 64;

    // DMA slab s into buffer b: 2 instrs/thread, wave moves 8 rows x 256B
    auto stage = [&](int s, int b) {
        #pragma unroll
        for (int t = 0; t < 2; ++t) {
            int r0  = (wave * 2 + t) * 4;            // wave-uniform base row
            int row = r0 + (lane >> 4);
            int gch = (lane & 15) ^ (row & 15);      // swizzled source chunk
            gl_lds16(&A[(size_t)(rowBase + row) * K + s * 64 + gch * 4],
                     &Abuf[b][r0 * 64]);
        }
    };

    // A fragment: row = rg*32 + mf*16 + c16 (row&15 == c16)
    auto aFrag = [&](int b, int mf, int s2) -> bf16x8 {
        int row = rg * 32 + mf * 16 + c16;
        int e   = s2 * 8 + quad * 2;                 // even 16B-chunk index
        const float* base = &Abuf[b][row * 64];
        f32x4 lo = *reinterpret_cast<const f32x4*>(base + ((e ^ c16) << 2));
        f32x4 hi = *reinterpret_cast<const f32x4*>(base + (((e + 1) ^ c16) << 2));
        return pack8(lo, hi);
    };

    const bf16_t* pB[4];
    #pragma unroll
    for (int nf = 0; nf < 4; ++nf)
        pB[nf] = Wt + (size_t)(cg * 4 + nf) * 16 * K + quad * 256 + c16 * 16;

    f32x4 acc[2][4] = {};
    stage(0, 0);

    for (int s = 0; s < S; ++s) {
        const int b = s & 1;
        __syncthreads();                   // drains buf b's DMA (issued 1 iter ago)
        if (s + 1 < S) stage(s + 1, b ^ 1);
        #pragma unroll
        for (int s2 = 0; s2 < 2; ++s2) {
            bf16x8 bF[4];
            #pragma unroll
            for (int nf = 0; nf < 4; ++nf)
                bF[nf] = *reinterpret_cast<const bf16x8*>(pB[nf] + s * 1024 + s2 * 8);
            #pragma unroll
            for (int mf = 0; mf < 2; ++mf) {
                bf16x8 aF = aFrag(b, mf, s2);
                #pragma unroll
                for (int nf = 0; nf < 4; ++nf)
                    acc[mf][nf] = __builtin_amdgcn_mfma_f32_16x16x32_bf16(
                        aF, bF[nf], acc[mf][nf], 0, 0, 0);
            }
        }
    }

    // ---- epilogue: +bias, ssq, normalize, fp8 MX-frag store ----
    #pragma unroll
    for (int nf = 0; nf < 4; ++nf) {
        float bb = bias[cg * 64 + nf * 16 + c16];
        #pragma unroll
        for (int mf = 0; mf < 2; ++mf)
            #pragma unroll
            for (int r = 0; r < 4; ++r) acc[mf][nf][r] += bb;
    }

    #pragma unroll
    for (int mf = 0; mf < 2; ++mf)
        #pragma unroll
        for (int r = 0; r < 4; ++r) {
            float v = 0.f;
            #pragma unroll
            for (int nf = 0; nf < 4; ++nf) v += acc[mf][nf][r] * acc[mf][nf][r];
            v += __shfl_xor(v, 1, 64);
            v += __shfl_xor(v, 2, 64);
            v += __shfl_xor(v, 4, 64);
            v += __shfl_xor(v, 8, 64);
            if (c16 == 0) ssqL[cg][rg * 32 + mf * 16 + quad * 4 + r] = v;
        }
    __syncthreads();

    #pragma unroll
    for (int mf = 0; mf < 2; ++mf)
        #pragma unroll
        for (int r = 0; r < 4; ++r) {
            int lr = rg * 32 + mf * 16 + quad * 4 + r;
            float t = ssqL[0][lr] + ssqL[1][lr] + ssqL[2][lr] + ssqL[3][lr];
            float inv = 1.0f / fmaxf(sqrtf(t), 1e-8f);
            #pragma unroll
            for (int nf = 0; nf < 4; ++nf) {
                int k = cg * 64 + nf * 16 + c16;
                // MX K=128 operand layout: (k>>5)*512 + row16*32 + (k&31)
                obuf[((lr >> 4) << 12) + ((k >> 5) << 9) + ((lr & 15) << 5) + (k & 31)] =
                    cvt1_e4m3(acc[mf][nf][r] * inv);
            }
        }
    __syncthreads();

    // coalesced copy-out: 16 KB, 32 B/thread (tiles contiguous in global)
    const f32x4* src = reinterpret_cast<const f32x4*>(&obuf[tid * 32]);
    f32x4* g = reinterpret_cast<f32x4*>(dst + (size_t)rowBase * 256 + tid * 32);
    g[0] = src[0];
    g[1] = src[1];
}

// ---------------------------------------------------------------------------
// sim_gemm: e = exp(Xn @ Yn^T); partial rowsum/colsum/diag.
// ROUND 7: reduction-geometry swap. Block owns a FIXED 128-row block and
// walks 4 col-tiles (A resident in regs, B prefetched per tile). Per tile,
// the cross-lane reduce is COLSUM (quad-reduce: 8 bpermutes) instead of
// rowsum's c16-reduce (64 bpermutes); rowsum partials accumulate in
// registers across tiles and are shuffled ONCE per block. All reduce-adds
// as f32x4 vector ops (v_pk_add_f32). No sched_barrier (R6 spill lesson),
// no LDS, no atomics, coalesced private-slab stores (R5-proven).
// ---------------------------------------------------------------------------
__global__ __launch_bounds__(256, 2) void sim_gemm(
    const unsigned char* __restrict__ Xt, const unsigned char* __restrict__ Yt,
    float* __restrict__ rowsumP, float* __restrict__ colsumP,
    float* __restrict__ pos)
{
    const int tid  = threadIdx.x;
    const int lane = tid & 63;
    const int wave = tid >> 6;
    const int quad = lane >> 4;
    const int c16  = lane & 15;
    const int wy   = wave >> 1;
    const int wx   = wave & 1;

    // XCD swizzle: xcd = id&7 owns colGrps {xcd, xcd+8} -> Yt slice 256 KB
    // + full Xt 2 MB per XCD L2.
    const int id  = blockIdx.x;            // 0..1023
    const int idx = id >> 3;               // 0..127
    const int colGrp = ((idx >> 6) << 3) + (id & 7);   // 0..15
    const int rowBlk = idx & 63;                       // 0..63
    const int rowBase = rowBlk * 128;

    // ---- A fragments (fixed rows): load once ----
    i32x8 A0[4], A1[4];
    #pragma unroll
    for (int mf = 0; mf < 4; ++mf) {
        const i32x8* p = reinterpret_cast<const i32x8*>(
            Xt + (size_t)(rowBase + wy * 64 + mf * 16) * 256 + quad * 512 + c16 * 32);
        A0[mf] = p[0];
        A1[mf] = p[64];
    }

    auto bPtr = [&](int cBase, int nf) {
        return reinterpret_cast<const i32x8*>(
            Yt + (size_t)(cBase + wx * 64 + nf * 16) * 256 + quad * 512 + c16 * 32);
    };

    // ---- B fragments for tile 0 ----
    i32x8 B0[4], B1[4];
    #pragma unroll
    for (int nf = 0; nf < 4; ++nf) {
        const i32x8* p = bPtr(colGrp * 512, nf);
        B0[nf] = p[0];
        B1[nf] = p[64];
    }

    f32x4 rr[4] = {};   // rowsum partials, register-accumulated across tiles

    for (int t = 0; t < 4; ++t) {
        const int cBase = colGrp * 512 + t * 128;

        f32x4 acc[4][4] = {};
        __builtin_amdgcn_s_setprio(1);
        #pragma unroll
        for (int mf = 0; mf < 4; ++mf)
            #pragma unroll
            for (int nf = 0; nf < 4; ++nf)
                acc[mf][nf] = __builtin_amdgcn_mfma_scale_f32_16x16x128_f8f6f4(
                    A0[mf], B0[nf], acc[mf][nf], 0, 0, 0, 127, 0, 127);
        #pragma unroll
        for (int mf = 0; mf < 4; ++mf)
            #pragma unroll
            for (int nf = 0; nf < 4; ++nf)
                acc[mf][nf] = __builtin_amdgcn_mfma_scale_f32_16x16x128_f8f6f4(
                    A1[mf], B1[nf], acc[mf][nf], 0, 0, 0, 127, 0, 127);
        __builtin_amdgcn_s_setprio(0);

        // ---- prefetch next tile's B (epilogue covers L2 latency) ----
        if (t < 3) {
            #pragma unroll
            for (int nf = 0; nf < 4; ++nf) {
                const i32x8* p = bPtr(cBase + 128, nf);
                B0[nf] = p[0];
                B1[nf] = p[64];
            }
        }

        // ---- exp (TAU = 1) ----
        #pragma unroll
        for (int mf = 0; mf < 4; ++mf)
            #pragma unroll
            for (int nf = 0; nf < 4; ++nf)
                #pragma unroll
                for (int r = 0; r < 4; ++r)
                    acc[mf][nf][r] = __expf(acc[mf][nf][r]);

        if (rowBase == cBase) {
            #pragma unroll
            for (int mf = 0; mf < 4; ++mf)
                #pragma unroll
                for (int nf = 0; nf < 4; ++nf)
                    #pragma unroll
                    for (int r = 0; r < 4; ++r) {
                        int lrow = wy * 64 + mf * 16 + quad * 4 + r;
                        int lcol = wx * 64 + nf * 16 + c16;
                        if (lrow == lcol) pos[rowBase + lrow] = acc[mf][nf][r];
                    }
        }

        // ---- per-tile COLSUM: vector adds + horizontal + quad-reduce ----
        float cst[4];
        #pragma unroll
        for (int nf = 0; nf < 4; ++nf) {
            f32x4 tv = (acc[0][nf] + acc[1][nf]) + (acc[2][nf] + acc[3][nf]);
            float s = (tv[0] + tv[1]) + (tv[2] + tv[3]);
            s += __shfl_xor(s, 16, 64);
            s += __shfl_xor(s, 32, 64);
            cst[nf] = s;
        }
        // lane L holds col wx*64+L -> select cst[L>>4]; coalesced store.
        float csel = cst[0];
        #pragma unroll
        for (int k = 1; k < 4; ++k)
            csel = (quad == k) ? cst[k] : csel;
        colsumP[(size_t)(rowBlk * 2 + wy) * 8192 + cBase + wx * 64 + lane] = csel;

        // ---- rowsum: register accumulation (vector adds) ----
        #pragma unroll
        for (int mf = 0; mf < 4; ++mf)
            rr[mf] += (acc[mf][0] + acc[mf][1]) + (acc[mf][2] + acc[mf][3]);
    }

    // ---- rowsum finish (once per block): c16-reduce + lane transpose ----
    float rs[4][4];
    #pragma unroll
    for (int mf = 0; mf < 4; ++mf)
        #pragma unroll
        for (int r = 0; r < 4; ++r) {
            float v = rr[mf][r];
            v += __shfl_xor(v, 1, 64);
            v += __shfl_xor(v, 2, 64);
            v += __shfl_xor(v, 4, 64);
            v += __shfl_xor(v, 8, 64);
            rs[mf][r] = v;
        }
    // Register lane-transpose (R4/R5 harness-verified): lane L ends with
    // the sum for row wy*64+L.
    float vsel = rs[0][0];
    #pragma unroll
    for (int k = 1; k < 16; ++k)
        vsel = (c16 == k) ? rs[k >> 2][k & 3] : vsel;
    int srcLane = ((lane >> 2) & 3) * 16 + (lane >> 4) * 4 + (lane & 3);
    float rowv = __shfl(vsel, srcLane, 64);
    rowsumP[(size_t)(colGrp * 2 + wx) * 8192 + rowBase + wy * 64 + lane] = rowv;
}

// ---------------------------------------------------------------------------
// finalize: parallelized slab reduction. 256 blocks x 256 threads; each
// block owns 32 outputs, 8 threads per output (coalesced slab-major reads),
// LDS combine, then the log expression. rowsum: 32 slabs; colsum: 128.
// ---------------------------------------------------------------------------
__global__ __launch_bounds__(256) void finalize(
    const float* __restrict__ rowsumP, const float* __restrict__ colsumP,
    const float* __restrict__ pos, float* __restrict__ out)
{
    __shared__ float redR[256], redC[256];

    const int oi   = threadIdx.x & 31;      // output within block
    const int part = threadIdx.x >> 5;      // 0..7
    const int i    = blockIdx.x * 32 + oi;

    float r = 0.f;
    #pragma unroll
    for (int c = part; c < 32; c += 8)
        r += rowsumP[(size_t)c * 8192 + i];

    float cv = 0.f;
    #pragma unroll
    for (int g = part; g < 128; g += 8)
        cv += colsumP[(size_t)g * 8192 + i];

    redR[threadIdx.x] = r;
    redC[threadIdx.x] = cv;
    __syncthreads();

    if (threadIdx.x < 32) {
        float rsum = 0.f, csum = 0.f;
        #pragma unroll
        for (int p = 0; p < 8; ++p) {
            rsum += redR[oi + 32 * p];
            csum += redC[oi + 32 * p];
        }
        float p = pos[i];
        out[i] = logf(csum - p) + logf(rsum - p) - 2.0f * logf(p);
    }
}

// ---------------------------------------------------------------------------
extern "C" void kernel_launch(void* const* d_in, const int* in_sizes, int n_in,
                              void* d_out, int out_size, void* d_ws, size_t ws_size,
                              hipStream_t stream) {
    const float* X  = (const float*)d_in[0];
    const float* Y  = (const float*)d_in[1];
    const float* Wx = (const float*)d_in[2];
    const float* bx = (const float*)d_in[3];
    const float* Wy = (const float*)d_in[4];
    const float* by = (const float*)d_in[5];
    float* out = (float*)d_out;

    char* ws = (char*)d_ws;
    unsigned char* Xt  = (unsigned char*)(ws);               // 2 MB fp8 MX frag-major
    unsigned char* Yt  = (unsigned char*)(ws + (2u << 20));  // 2 MB
    bf16_t*        Wxt = (bf16_t*)(ws + (4u << 20));         // 512 KB bf16 frag-major
    bf16_t*        Wyt = (bf16_t*)(ws + (4u << 20) + (512u << 10));  // 384 KB
    float* rowsumP = (float*)(ws + (5u << 20));              //  32 x 8192 f32 = 1 MB
    float* colsumP = (float*)(ws + (6u << 20));              // 128 x 8192 f32 = 4 MB
    float* pos     = (float*)(ws + (10u << 20));             // 32 KB

    wconv<<<224, 256, 0, stream>>>(Wx, Wy, Wxt, Wyt);
    proj_norm<<<256, 512, 0, stream>>>(X, Y, Wxt, bx, Wyt, by, Xt, Yt);
    sim_gemm<<<1024, 256, 0, stream>>>(Xt, Yt, rowsumP, colsumP, pos);
    finalize<<<256, 256, 0, stream>>>(rowsumP, colsumP, pos, out);
}

// Round 8
// 154.326 us; speedup vs baseline: 1.2252x; 1.1935x over previous
//
#include <hip/hip_runtime.h>
#include <hip/hip_bf16.h>

typedef __bf16 bf16_t;
typedef __bf16 bf16x8 __attribute__((ext_vector_type(8)));
typedef float  f32x4  __attribute__((ext_vector_type(4)));
typedef int    i32x8  __attribute__((ext_vector_type(8)));

__device__ __forceinline__ bf16x8 pack8(f32x4 a, f32x4 b) {
    bf16x8 h = { (bf16_t)a.x, (bf16_t)a.y, (bf16_t)a.z, (bf16_t)a.w,
                 (bf16_t)b.x, (bf16_t)b.y, (bf16_t)b.z, (bf16_t)b.w };
    return h;
}

// 16B async global->LDS DMA. LDS dest is wave-uniform base + lane*16.
__device__ __forceinline__ void gl_lds16(const void* g, void* l) {
    __builtin_amdgcn_global_load_lds(
        (const __attribute__((address_space(1))) unsigned int*)g,
        (__attribute__((address_space(3))) unsigned int*)l, 16, 0, 0);
}

// ---- fp8 e4m3 (OCP) conversion ----
#if __has_builtin(__builtin_amdgcn_cvt_pk_fp8_f32)
__device__ __forceinline__ unsigned char cvt1_e4m3(float x) {
    return (unsigned char)(__builtin_amdgcn_cvt_pk_fp8_f32(x, x, 0, false) & 0xff);
}
#else
__device__ __forceinline__ unsigned char cvt1_e4m3(float x) {
    unsigned u = __float_as_uint(x);
    unsigned sign = (u >> 24) & 0x80u;
    float a = fabsf(x);
    if (a < 7.8125e-3f) { int q = (int)(a * 512.0f + 0.5f); return (unsigned char)(sign | q); }
    if (a >= 448.0f) return (unsigned char)(sign | 0x7E);
    unsigned au = u & 0x7FFFFFFFu;
    unsigned lsb = (au >> 20) & 1u;
    au += 0x7FFFFu + lsb;
    int exp = (int)(au >> 23) - 127;
    unsigned man = (au >> 20) & 7u;
    return (unsigned char)(sign | ((unsigned)(exp + 7) << 3) | man);
}
#endif

// Fragment-major ELEMENT offset within a 16-row tile (any K) — bf16 16x16x32
// operand layout (used for W only).
__device__ __forceinline__ int frag_off_k(int row16, int k) {
    return ((k >> 6) << 10) + (((k >> 3) & 3) << 8) + (row16 << 4)
         + (((k >> 5) & 1) << 3) + (k & 7);
}

// ---------------------------------------------------------------------------
// wconv: W (fp32 [256,K]) -> fragment-major bf16. Also zeroes rowsum/colsum.
// (R2 verbatim.)
// ---------------------------------------------------------------------------
__global__ __launch_bounds__(256) void wconv(
    const float* __restrict__ Wx, const float* __restrict__ Wy,
    bf16_t* __restrict__ Wxt, bf16_t* __restrict__ Wyt,
    float* __restrict__ sums)
{
    int id = blockIdx.x * 256 + threadIdx.x;
    if (blockIdx.x < 64) sums[id] = 0.0f;

    int row, k0, K;
    const float* W;
    bf16_t* Wt;
    if (id < 32768) { W = Wx; Wt = Wxt; K = 1024; row = id >> 7; k0 = (id & 127) << 3; }
    else { int c = id - 32768; W = Wy; Wt = Wyt; K = 768; row = c / 96; k0 = (c % 96) << 3; }

    f32x4 lo = *reinterpret_cast<const f32x4*>(&W[(size_t)row * K + k0]);
    f32x4 hi = *reinterpret_cast<const f32x4*>(&W[(size_t)row * K + k0 + 4]);
    size_t off = (size_t)(row >> 4) * 16 * K + frag_off_k(row & 15, k0);
    *reinterpret_cast<bf16x8*>(Wt + off) = pack8(lo, hi);
}

// ---------------------------------------------------------------------------
// proj_norm: P = A@W^T + bias -> L2 row-normalize -> fp8 MX-frag store.
// ROUND 8: 2 blocks/CU. Block halved to 32 rows x 256 cols (256 thr, 4
// waves, wave tile 32x64), grid doubled to 512 -> two independent blocks
// per CU so one block's MFMA/epilogue covers the other's DMA-barrier
// drain + HBM latency. All mechanisms (DMA swizzle, fragment math, obuf)
// preserved with rg eliminated; LDS 25 KB/block.
// ---------------------------------------------------------------------------
__global__ __launch_bounds__(256, 4) void proj_norm(
    const float* __restrict__ X, const float* __restrict__ Y,
    const bf16_t* __restrict__ Wxt, const float* __restrict__ bxp,
    const bf16_t* __restrict__ Wyt, const float* __restrict__ byp,
    unsigned char* __restrict__ Xt, unsigned char* __restrict__ Yt)
{
    __shared__ float Abuf[2][32 * 64];       // 8 KB x2, chunk-XOR swizzled
    __shared__ unsigned char obuf[8192];     // 32x256 fp8 frag-major (MX layout)
    __shared__ float ssqL[4][32];            // [colGroup][row]

    const int tid  = threadIdx.x;
    const int lane = tid & 63;
    const int wave = tid >> 6;     // 0..3
    const int quad = lane >> 4;
    const int c16  = lane & 15;
    const int cg   = wave;         // 0..3: cols cg*64

    const bool isY = blockIdx.x >= 256;
    const float*  A    = isY ? Y   : X;
    const bf16_t* Wt   = isY ? Wyt : Wxt;
    const float*  bias = isY ? byp : bxp;
    unsigned char* dst = isY ? Yt  : Xt;
    const int K = isY ? 768 : 1024;
    const int S = K >> 6;           // 64-K slabs
    const int rowBase = (blockIdx.x & 255) * 32;

    // DMA slab s into buffer b: 2 instrs/thread, wave moves 8 rows x 256B
    auto stage = [&](int s, int b) {
        #pragma unroll
        for (int t = 0; t < 2; ++t) {
            int r0  = (wave * 2 + t) * 4;            // wave-uniform base row (0..28)
            int row = r0 + (lane >> 4);
            int gch = (lane & 15) ^ (row & 15);      // swizzled source chunk
            gl_lds16(&A[(size_t)(rowBase + row) * K + s * 64 + gch * 4],
                     &Abuf[b][r0 * 64]);
        }
    };

    // A fragment: row = mf*16 + c16 (row&15 == c16)
    auto aFrag = [&](int b, int mf, int s2) -> bf16x8 {
        int row = mf * 16 + c16;
        int e   = s2 * 8 + quad * 2;                 // even 16B-chunk index
        const float* base = &Abuf[b][row * 64];
        f32x4 lo = *reinterpret_cast<const f32x4*>(base + ((e ^ c16) << 2));
        f32x4 hi = *reinterpret_cast<const f32x4*>(base + (((e + 1) ^ c16) << 2));
        return pack8(lo, hi);
    };

    const bf16_t* pB[4];
    #pragma unroll
    for (int nf = 0; nf < 4; ++nf)
        pB[nf] = Wt + (size_t)(cg * 4 + nf) * 16 * K + quad * 256 + c16 * 16;

    f32x4 acc[2][4] = {};
    stage(0, 0);

    for (int s = 0; s < S; ++s) {
        const int b = s & 1;
        __syncthreads();                   // drains buf b's DMA (issued 1 iter ago)
        if (s + 1 < S) stage(s + 1, b ^ 1);
        #pragma unroll
        for (int s2 = 0; s2 < 2; ++s2) {
            bf16x8 bF[4];
            #pragma unroll
            for (int nf = 0; nf < 4; ++nf)
                bF[nf] = *reinterpret_cast<const bf16x8*>(pB[nf] + s * 1024 + s2 * 8);
            #pragma unroll
            for (int mf = 0; mf < 2; ++mf) {
                bf16x8 aF = aFrag(b, mf, s2);
                #pragma unroll
                for (int nf = 0; nf < 4; ++nf)
                    acc[mf][nf] = __builtin_amdgcn_mfma_f32_16x16x32_bf16(
                        aF, bF[nf], acc[mf][nf], 0, 0, 0);
            }
        }
    }

    // ---- epilogue: +bias, ssq, normalize, fp8 MX-frag store ----
    #pragma unroll
    for (int nf = 0; nf < 4; ++nf) {
        float bb = bias[cg * 64 + nf * 16 + c16];
        #pragma unroll
        for (int mf = 0; mf < 2; ++mf)
            #pragma unroll
            for (int r = 0; r < 4; ++r) acc[mf][nf][r] += bb;
    }

    #pragma unroll
    for (int mf = 0; mf < 2; ++mf)
        #pragma unroll
        for (int r = 0; r < 4; ++r) {
            float v = 0.f;
            #pragma unroll
            for (int nf = 0; nf < 4; ++nf) v += acc[mf][nf][r] * acc[mf][nf][r];
            v += __shfl_xor(v, 1, 64);
            v += __shfl_xor(v, 2, 64);
            v += __shfl_xor(v, 4, 64);
            v += __shfl_xor(v, 8, 64);
            if (c16 == 0) ssqL[cg][mf * 16 + quad * 4 + r] = v;
        }
    __syncthreads();

    #pragma unroll
    for (int mf = 0; mf < 2; ++mf)
        #pragma unroll
        for (int r = 0; r < 4; ++r) {
            int lr = mf * 16 + quad * 4 + r;
            float t = ssqL[0][lr] + ssqL[1][lr] + ssqL[2][lr] + ssqL[3][lr];
            float inv = 1.0f / fmaxf(sqrtf(t), 1e-8f);
            #pragma unroll
            for (int nf = 0; nf < 4; ++nf) {
                int k = cg * 64 + nf * 16 + c16;
                // MX K=128 operand layout: (k>>5)*512 + row16*32 + (k&31)
                obuf[((lr >> 4) << 12) + ((k >> 5) << 9) + ((lr & 15) << 5) + (k & 31)] =
                    cvt1_e4m3(acc[mf][nf][r] * inv);
            }
        }
    __syncthreads();

    // coalesced copy-out: 8 KB, 32 B/thread (tiles contiguous in global)
    const f32x4* src = reinterpret_cast<const f32x4*>(&obuf[tid * 32]);
    f32x4* g = reinterpret_cast<f32x4*>(dst + (size_t)rowBase * 256 + tid * 32);
    g[0] = src[0];
    g[1] = src[1];
}

// ---------------------------------------------------------------------------
// sim_gemm (R2 VERBATIM — best harness-verified config, 42.2 us):
// MX-scaled fp8 K=128 MFMA (unit scales). Each block: one 128-col block,
// FOUR consecutive 128-row tiles. B in registers; A prefetched under the
// epilogue; LDS pre-reduction -> coalesced 128-thread atomics.
// ---------------------------------------------------------------------------
__global__ __launch_bounds__(256, 2) void sim_gemm(
    const unsigned char* __restrict__ Xt, const unsigned char* __restrict__ Yt,
    float* __restrict__ rowsum, float* __restrict__ colsum,
    float* __restrict__ pos)
{
    __shared__ float red2[2][128];   // [wx][row] rowsum partials (reused for colsum)

    const int tid  = threadIdx.x;
    const int lane = tid & 63;
    const int wave = tid >> 6;
    const int quad = lane >> 4;
    const int c16  = lane & 15;
    const int wy   = wave >> 1;
    const int wx   = wave & 1;

    // id&7 = XCD; each XCD: 8 colBlks x 16 row-groups (x4 tiles each).
    const int id = blockIdx.x;                     // 0..1023
    const int b2 = id >> 3;                        // 0..127
    const int colBlk = (id & 7) * 8 + (b2 >> 4);   // 0..63
    const int rowGrp = b2 & 15;                    // 0..15 -> rows rowGrp*512..
    const int colBase = colBlk * 128;

    // ---- B fragments: load once ----
    i32x8 B0[4], B1[4];
    #pragma unroll
    for (int nf = 0; nf < 4; ++nf) {
        const i32x8* p = reinterpret_cast<const i32x8*>(
            Yt + (size_t)(colBase + wx * 64 + nf * 16) * 256 + quad * 512 + c16 * 32);
        B0[nf] = p[0];
        B1[nf] = p[64];
    }

    auto aPtr = [&](int rowBase, int mf) {
        return reinterpret_cast<const i32x8*>(
            Xt + (size_t)(rowBase + wy * 64 + mf * 16) * 256 + quad * 512 + c16 * 32);
    };

    // ---- A fragments for tile 0 ----
    i32x8 A0[4], A1[4];
    #pragma unroll
    for (int mf = 0; mf < 4; ++mf) {
        const i32x8* p = aPtr(rowGrp * 512, mf);
        A0[mf] = p[0];
        A1[mf] = p[64];
    }

    float cs[4] = {0.f, 0.f, 0.f, 0.f};   // per-lane colsum partials across tiles

    for (int t = 0; t < 4; ++t) {
        const int rowBase = rowGrp * 512 + t * 128;

        f32x4 acc[4][4] = {};
        #pragma unroll
        for (int mf = 0; mf < 4; ++mf)
            #pragma unroll
            for (int nf = 0; nf < 4; ++nf)
                acc[mf][nf] = __builtin_amdgcn_mfma_scale_f32_16x16x128_f8f6f4(
                    A0[mf], B0[nf], acc[mf][nf], 0, 0, 0, 127, 0, 127);
        #pragma unroll
        for (int mf = 0; mf < 4; ++mf)
            #pragma unroll
            for (int nf = 0; nf < 4; ++nf)
                acc[mf][nf] = __builtin_amdgcn_mfma_scale_f32_16x16x128_f8f6f4(
                    A1[mf], B1[nf], acc[mf][nf], 0, 0, 0, 127, 0, 127);

        // ---- prefetch next tile's A (overwrites A regs; epilogue covers latency)
        if (t < 3) {
            #pragma unroll
            for (int mf = 0; mf < 4; ++mf) {
                const i32x8* p = aPtr(rowBase + 128, mf);
                A0[mf] = p[0];
                A1[mf] = p[64];
            }
        }

        // ---- epilogue ----
        #pragma unroll
        for (int mf = 0; mf < 4; ++mf)
            #pragma unroll
            for (int nf = 0; nf < 4; ++nf)
                #pragma unroll
                for (int r = 0; r < 4; ++r)
                    acc[mf][nf][r] = __expf(acc[mf][nf][r]);   // TAU = 1

        if (rowBase == colBase) {
            #pragma unroll
            for (int mf = 0; mf < 4; ++mf)
                #pragma unroll
                for (int nf = 0; nf < 4; ++nf)
                    #pragma unroll
                    for (int r = 0; r < 4; ++r) {
                        int lrow = wy * 64 + mf * 16 + quad * 4 + r;
                        int lcol = wx * 64 + nf * 16 + c16;
                        if (lrow == lcol) pos[rowBase + lrow] = acc[mf][nf][r];
                    }
        }

        // rowsum partial for this wave's 64 columns (shuffle over c16)
        float rs[4][4];
        #pragma unroll
        for (int mf = 0; mf < 4; ++mf)
            #pragma unroll
            for (int r = 0; r < 4; ++r) {
                float v = acc[mf][0][r] + acc[mf][1][r] + acc[mf][2][r] + acc[mf][3][r];
                v += __shfl_xor(v, 1, 64);
                v += __shfl_xor(v, 2, 64);
                v += __shfl_xor(v, 4, 64);
                v += __shfl_xor(v, 8, 64);
                rs[mf][r] = v;
            }

        // colsum per-lane partials accumulate in regs (reduced after loop)
        #pragma unroll
        for (int nf = 0; nf < 4; ++nf) {
            float v = 0.f;
            #pragma unroll
            for (int mf = 0; mf < 4; ++mf)
                #pragma unroll
                for (int r = 0; r < 4; ++r)
                    v += acc[mf][nf][r];
            cs[nf] += v;
        }

        __syncthreads();   // red2 readers of tile t-1 are done
        if (c16 == 0) {
            #pragma unroll
            for (int mf = 0; mf < 4; ++mf)
                #pragma unroll
                for (int r = 0; r < 4; ++r)
                    red2[wx][wy * 64 + mf * 16 + quad * 4 + r] = rs[mf][r];
        }
        __syncthreads();
        if (tid < 128)
            atomicAdd(&rowsum[rowBase + tid], red2[0][tid] + red2[1][tid]);
    }

    // ---- colsum: reduce across quads, combine the two wy waves via LDS ----
    float csr[4];
    #pragma unroll
    for (int nf = 0; nf < 4; ++nf) {
        float v = cs[nf];
        v += __shfl_xor(v, 16, 64);
        v += __shfl_xor(v, 32, 64);
        csr[nf] = v;
    }
    __syncthreads();   // last rowsum reads done; reuse red2
    if (quad == 0) {
        #pragma unroll
        for (int nf = 0; nf < 4; ++nf)
            red2[wy][wx * 64 + nf * 16 + c16] = csr[nf];
    }
    __syncthreads();
    if (tid < 128)
        atomicAdd(&colsum[colBase + tid], red2[0][tid] + red2[1][tid]);
}

// ---------------------------------------------------------------------------
__global__ __launch_bounds__(256) void finalize(
    const float* __restrict__ rowsum, const float* __restrict__ colsum,
    const float* __restrict__ pos, float* __restrict__ out)
{
    int i = blockIdx.x * 256 + threadIdx.x;
    float p = pos[i];
    out[i] = logf(colsum[i] - p) + logf(rowsum[i] - p) - 2.0f * logf(p);
}

// ---------------------------------------------------------------------------
extern "C" void kernel_launch(void* const* d_in, const int* in_sizes, int n_in,
                              void* d_out, int out_size, void* d_ws, size_t ws_size,
                              hipStream_t stream) {
    const float* X  = (const float*)d_in[0];
    const float* Y  = (const float*)d_in[1];
    const float* Wx = (const float*)d_in[2];
    const float* bx = (const float*)d_in[3];
    const float* Wy = (const float*)d_in[4];
    const float* by = (const float*)d_in[5];
    float* out = (float*)d_out;

    char* ws = (char*)d_ws;
    unsigned char* Xt  = (unsigned char*)(ws);               // 2 MB fp8 MX frag-major
    unsigned char* Yt  = (unsigned char*)(ws + (2u << 20));  // 2 MB
    bf16_t*        Wxt = (bf16_t*)(ws + (4u << 20));         // 512 KB bf16 frag-major
    bf16_t*        Wyt = (bf16_t*)(ws + (4u << 20) + (512u << 10));  // 384 KB
    float* rowsum = (float*)(ws + (5u << 20));
    float* colsum = rowsum + 8192;
    float* pos    = colsum + 8192;

    wconv<<<224, 256, 0, stream>>>(Wx, Wy, Wxt, Wyt, rowsum);
    proj_norm<<<512, 256, 0, stream>>>(X, Y, Wxt, bx, Wyt, by, Xt, Yt);
    sim_gemm<<<1024, 256, 0, stream>>>(Xt, Yt, rowsum, colsum, pos);
    finalize<<<32, 256, 0, stream>>>(rowsum, colsum, pos, out);
}